// Round 3
// baseline (80.975 us; speedup 1.0000x reference)
//
#include <hip/hip_runtime.h>

#define NORB 13
#define FEAT 107
#define TWO_PI 6.28318530717958647692f
#define NN 3328                 // 256 atoms * 13 orbitals
#define NN2 (NN * NN)           // 11,075,584 complex per k-matrix

// Per-thread computation of the (p,q) -> feature-index map for the
// upper-tri orbital-pair layout. Basis l=[0,0,1,1,2], dims [1,1,3,3,5].
__device__ __forceinline__ void map_pq(int p, int q, int& idx, float& scl) {
    const int DIMS[5] = {1, 1, 3, 3, 5};
    const int OFFS[5] = {0, 1, 2, 5, 8};
    idx = -1; scl = 0.0f;
    int o = 0;
    #pragma unroll
    for (int i = 0; i < 5; ++i) {
        #pragma unroll
        for (int j = i; j < 5; ++j) {
            int di = DIMS[i], dj = DIMS[j];
            if (p >= OFFS[i] && p < OFFS[i] + di && q >= OFFS[j] && q < OFFS[j] + dj) {
                idx = o + (p - OFFS[i]) * dj + (q - OFFS[j]);
                scl = (i == j) ? 0.5f : 1.0f;
            }
            o += di * dj;
        }
    }
}

// ============================ FAST PATH =====================================

// init: head[65536] = -1 (int4 stores), prefill diagonal pairs, counter = 256.
__global__ void init_kernel(int4* __restrict__ head4, int* __restrict__ pairlist,
                            int* __restrict__ counter) {
    int t = blockIdx.x * blockDim.x + threadIdx.x;   // 16384 threads exactly
    head4[t] = make_int4(-1, -1, -1, -1);
    if (t < 256) pairlist[t] = t * 257;              // diagonal pair ids
    if (t == 0) *counter = 256;
}

// fill: per directed edge entry, chain into head[] lists; first claimer of an
// off-diagonal pair appends it to pairlist. dir==0 threads also cache phases.
__global__ void fill_kernel(const int* __restrict__ eidx, const float* __restrict__ kpt,
                            const float* __restrict__ shf,
                            int* __restrict__ head, int* __restrict__ nxt,
                            int* __restrict__ pairlist, int* __restrict__ counter,
                            float* __restrict__ phases, int E, int K) {
    int tid = blockIdx.x * blockDim.x + threadIdx.x;
    if (tid >= 2 * E) return;
    int e = tid >> 1, dir = tid & 1;
    int ei = eidx[e], ej = eidx[E + e];
    int a = dir ? ej : ei;
    int b = dir ? ei : ej;
    int pid = a * 256 + b;
    int old = atomicExch(&head[pid], tid);
    nxt[tid] = old;
    if (old < 0 && a != b) {
        int pos = atomicAdd(counter, 1);
        pairlist[pos] = pid;
    }
    if (dir == 0) {
        float rx = shf[e * 3 + 0], ry = shf[e * 3 + 1], rz = shf[e * 3 + 2];
        for (int k = 0; k < K; ++k) {
            float th = -TWO_PI * (kpt[k * 3] * rx + kpt[k * 3 + 1] * ry + kpt[k * 3 + 2] * rz);
            float s, c;
            __sincosf(th, &s, &c);
            phases[(e * K + k) * 2]     = c;
            phases[(e * K + k) * 2 + 1] = s;
        }
    }
}

// gated zero: stream zeros, skipping float4s that lie entirely inside painted
// blocks (painted = diagonal or has an edge-list head). All 32-bit arithmetic.
__global__ void zero_gated_kernel(float4* __restrict__ out4, const int* __restrict__ head,
                                  long n4) {
    long i = (long)blockIdx.x * blockDim.x + threadIdx.x;
    long stride = (long)gridDim.x * blockDim.x;
    float4 z = make_float4(0.f, 0.f, 0.f, 0.f);
    for (; i < n4; i += stride) {
        unsigned ci  = (unsigned)(i * 2);        // complex index (k folded out by %)
        unsigned rem = ci % NN2;
        unsigned row = rem / NN;
        unsigned c   = rem - row * NN;
        unsigned a   = row / 13u;
        unsigned b0  = c / 13u;
        unsigned b1  = (c + 1u) / 13u;           // float4 = 2 complex, same row
        bool p0 = (a == b0) || head[a * 256u + b0] >= 0;
        bool p1 = (b1 == b0) ? p0 : ((a == b1) || head[a * 256u + b1] >= 0);
        if (!(p0 && p1)) out4[i] = z;
    }
}

// paint: one workgroup per distinct nonzero block pair; sum list in registers,
// plain stores (each painted element written exactly once, all 4 k's).
__global__ void paint_kernel(const float* __restrict__ hop, const float* __restrict__ ons,
                             const int* __restrict__ head, const int* __restrict__ nxt,
                             const int* __restrict__ pairlist, const int* __restrict__ counter,
                             const float* __restrict__ phases, float* __restrict__ out,
                             int K) {
    int w = blockIdx.x;
    if (w >= *counter) return;
    int t = threadIdx.x;
    if (t >= NORB * NORB) return;
    int pid = pairlist[w];
    int a = pid >> 8, b = pid & 255;
    int p = t / NORB, q = t - p * NORB;
    int i0, i1; float s0, s1;
    map_pq(p, q, i0, s0);   // entry (p,q) of assembled block
    map_pq(q, p, i1, s1);   // entry (q,p) — for transposed contributions
    float ar[4] = {0.f, 0.f, 0.f, 0.f}, ai[4] = {0.f, 0.f, 0.f, 0.f};
    if (a == b) {
        const float* f = ons + (long)a * FEAT;
        float v = 0.f;
        if (i0 >= 0) v += s0 * f[i0];
        if (i1 >= 0) v += s1 * f[i1];
        #pragma unroll
        for (int k = 0; k < 4; ++k) ar[k] += v;
    }
    for (int it = head[pid]; it >= 0; it = nxt[it]) {
        int e = it >> 1, dir = it & 1;
        float hv;
        if (dir == 0) hv = (i0 >= 0) ? s0 * hop[(long)e * FEAT + i0] : 0.f;
        else          hv = (i1 >= 0) ? s1 * hop[(long)e * FEAT + i1] : 0.f;
        const float* ph = phases + (long)e * K * 2;
        if (dir == 0) {
            #pragma unroll
            for (int k = 0; k < 4; ++k) { ar[k] += ph[2 * k] * hv; ai[k] += ph[2 * k + 1] * hv; }
        } else {        // conj(phase) * hop^T
            #pragma unroll
            for (int k = 0; k < 4; ++k) { ar[k] += ph[2 * k] * hv; ai[k] -= ph[2 * k + 1] * hv; }
        }
    }
    long row = (long)a * NORB + p;
    long col = (long)b * NORB + q;
    #pragma unroll
    for (int k = 0; k < 4; ++k) {
        long off = (((long)k * NN + row) * NN + col) * 2;
        out[off]     = ar[k];
        out[off + 1] = ai[k];
    }
}

// ============================ FALLBACK PATH (round-2, proven) ================

__global__ void zero_kernel(float4* __restrict__ out, long n4) {
    long i = (long)blockIdx.x * blockDim.x + threadIdx.x;
    long stride = (long)gridDim.x * blockDim.x;
    float4 z = make_float4(0.f, 0.f, 0.f, 0.f);
    for (; i < n4; i += stride) out[i] = z;
}

template <int CPX>
__global__ void onsite_kernel(const float* __restrict__ onsite, float* __restrict__ out,
                              int K, long nn) {
    int a = blockIdx.x;
    int t = threadIdx.x;
    if (t >= NORB * NORB) return;
    int p = t / NORB, q = t % NORB;
    int i1, i2; float s1, s2;
    map_pq(p, q, i1, s1);
    map_pq(q, p, i2, s2);
    const float* f = onsite + (long)a * FEAT;
    float v = 0.0f;
    if (i1 >= 0) v += s1 * f[i1];
    if (i2 >= 0) v += s2 * f[i2];
    long row = (long)a * NORB + p;
    long col = (long)a * NORB + q;
    for (int k = 0; k < K; ++k) {
        long off = (((long)k * nn + row) * nn + col) * CPX;
        out[off] = v;
    }
}

template <int CPX>
__global__ void edge_kernel(const float* __restrict__ hop, const float* __restrict__ kpts,
                            const float* __restrict__ shift, const int* __restrict__ eidx,
                            float* __restrict__ out, int E, int K, long nn) {
    int e = blockIdx.x;
    int t = threadIdx.x;
    __shared__ float phc[16], phs[16];
    int ei = eidx[e];
    int ej = eidx[E + e];
    if (t < K && t < 16) {
        float rx = shift[(long)e * 3 + 0];
        float ry = shift[(long)e * 3 + 1];
        float rz = shift[(long)e * 3 + 2];
        float th = -TWO_PI * (kpts[t * 3 + 0] * rx + kpts[t * 3 + 1] * ry + kpts[t * 3 + 2] * rz);
        float s, c;
        __sincosf(th, &s, &c);
        phc[t] = c; phs[t] = s;
    }
    __syncthreads();
    if (t >= NORB * NORB) return;
    int p = t / NORB, q = t % NORB;
    int idx; float scl;
    map_pq(p, q, idx, scl);
    if (idx < 0) return;
    float v = scl * hop[(long)e * FEAT + idx];
    long r1 = (long)ei * NORB + p, c1 = (long)ej * NORB + q;
    long r2 = (long)ej * NORB + q, c2 = (long)ei * NORB + p;
    for (int k = 0; k < K; ++k) {
        float pr = phc[k], pi = phs[k];
        long o1 = (((long)k * nn + r1) * nn + c1) * CPX;
        long o2 = (((long)k * nn + r2) * nn + c2) * CPX;
        atomicAdd(&out[o1], pr * v);
        atomicAdd(&out[o2], pr * v);
        if (CPX == 2) {
            atomicAdd(&out[o1 + 1], pi * v);
            atomicAdd(&out[o2 + 1], -pi * v);
        }
    }
}

// ============================================================================

extern "C" void kernel_launch(void* const* d_in, const int* in_sizes, int n_in,
                              void* d_out, int out_size, void* d_ws, size_t ws_size,
                              hipStream_t stream) {
    const float* hop  = (const float*)d_in[0];
    const float* ons  = (const float*)d_in[1];
    const float* kpt  = (const float*)d_in[2];
    const float* shf  = (const float*)d_in[3];
    const int*   eidx = (const int*)d_in[4];

    int E = in_sizes[0] / FEAT;    // 4096
    int N = in_sizes[1] / FEAT;    // 256
    int K = in_sizes[2] / 3;       // 4
    long nn = (long)N * NORB;      // 3328

    float* out = (float*)d_out;
    long knn2 = (long)K * nn * nn * 2;

    // Workspace carving (all 16B-aligned offsets)
    size_t off_head  = 0;                                  // 65536 ints
    size_t off_next  = off_head + 65536 * sizeof(int);     // 2E ints
    size_t off_plist = off_next + (size_t)2 * E * sizeof(int);      // 256+2E ints
    size_t off_cnt   = off_plist + (size_t)(256 + 2 * E) * sizeof(int);
    size_t off_phase = (off_cnt + 4 + 127) & ~(size_t)127; // E*K*2 floats
    size_t ws_need   = off_phase + (size_t)E * K * 2 * sizeof(float);

    bool fast = (N == 256) && (K == 4) && (nn == NN) &&
                ((long)out_size == knn2) && (ws_size >= ws_need);

    if (fast) {
        char* ws = (char*)d_ws;
        int*   head   = (int*)(ws + off_head);
        int*   nxt    = (int*)(ws + off_next);
        int*   plist  = (int*)(ws + off_plist);
        int*   cnt    = (int*)(ws + off_cnt);
        float* phases = (float*)(ws + off_phase);

        init_kernel<<<64, 256, 0, stream>>>((int4*)head, plist, cnt);
        int fill_blocks = (2 * E + 255) / 256;
        fill_kernel<<<fill_blocks, 256, 0, stream>>>(eidx, kpt, shf, head, nxt,
                                                     plist, cnt, phases, E, K);
        long n4 = (long)out_size / 4;
        zero_gated_kernel<<<2048, 256, 0, stream>>>((float4*)out, head, n4);
        paint_kernel<<<256 + 2 * E, 192, 0, stream>>>(hop, ons, head, nxt, plist,
                                                      cnt, phases, out, K);
    } else {
        // proven round-2 path
        int cpx = ((long)out_size >= knn2) ? 2 : 1;
        long n4 = (long)out_size / 4;
        zero_kernel<<<2048, 256, 0, stream>>>((float4*)out, n4);
        if (cpx == 2) {
            onsite_kernel<2><<<N, 192, 0, stream>>>(ons, out, K, nn);
            edge_kernel<2><<<E, 192, 0, stream>>>(hop, kpt, shf, eidx, out, E, K, nn);
        } else {
            onsite_kernel<1><<<N, 192, 0, stream>>>(ons, out, K, nn);
            edge_kernel<1><<<E, 192, 0, stream>>>(hop, kpt, shf, eidx, out, E, K, nn);
        }
    }
}

// Round 4
// 80.241 us; speedup vs baseline: 1.0091x; 1.0091x over previous
//
#include <hip/hip_runtime.h>

#define NORB 13
#define FEAT 107
#define TWO_PI 6.28318530717958647692f
#define NN 3328                 // 256 atoms * 13 orbitals
#define NROW 13312              // K * NN rows total (K=4)

// Per-thread computation of the (p,q) -> feature-index map for the
// upper-tri orbital-pair layout. Basis l=[0,0,1,1,2], dims [1,1,3,3,5].
__device__ __forceinline__ void map_pq(int p, int q, int& idx, float& scl) {
    const int DIMS[5] = {1, 1, 3, 3, 5};
    const int OFFS[5] = {0, 1, 2, 5, 8};
    idx = -1; scl = 0.0f;
    int o = 0;
    #pragma unroll
    for (int i = 0; i < 5; ++i) {
        #pragma unroll
        for (int j = i; j < 5; ++j) {
            int di = DIMS[i], dj = DIMS[j];
            if (p >= OFFS[i] && p < OFFS[i] + di && q >= OFFS[j] && q < OFFS[j] + dj) {
                idx = o + (p - OFFS[i]) * dj + (q - OFFS[j]);
                scl = (i == j) ? 0.5f : 1.0f;
            }
            o += di * dj;
        }
    }
}

// ============================ FAST PATH =====================================

// init: head[65536] = -1 (int4 stores), prefill diagonal pairs, counter = 256.
__global__ void init_kernel(int4* __restrict__ head4, int* __restrict__ pairlist,
                            int* __restrict__ counter) {
    int t = blockIdx.x * blockDim.x + threadIdx.x;   // 16384 threads exactly
    head4[t] = make_int4(-1, -1, -1, -1);
    if (t < 256) pairlist[t] = t * 257;              // diagonal pair ids
    if (t == 0) *counter = 256;
}

// fill: per directed edge entry, chain into head[] lists; first claimer of an
// off-diagonal pair appends it to pairlist. dir==0 threads also cache phases.
__global__ void fill_kernel(const int* __restrict__ eidx, const float* __restrict__ kpt,
                            const float* __restrict__ shf,
                            int* __restrict__ head, int* __restrict__ nxt,
                            int* __restrict__ pairlist, int* __restrict__ counter,
                            float* __restrict__ phases, int E, int K) {
    int tid = blockIdx.x * blockDim.x + threadIdx.x;
    if (tid >= 2 * E) return;
    int e = tid >> 1, dir = tid & 1;
    int ei = eidx[e], ej = eidx[E + e];
    int a = dir ? ej : ei;
    int b = dir ? ei : ej;
    int pid = a * 256 + b;
    int old = atomicExch(&head[pid], tid);
    nxt[tid] = old;
    if (old < 0 && a != b) {
        int pos = atomicAdd(counter, 1);
        pairlist[pos] = pid;
    }
    if (dir == 0) {
        float rx = shf[e * 3 + 0], ry = shf[e * 3 + 1], rz = shf[e * 3 + 2];
        for (int k = 0; k < K; ++k) {
            float th = -TWO_PI * (kpt[k * 3] * rx + kpt[k * 3 + 1] * ry + kpt[k * 3 + 2] * rz);
            float s, c;
            __sincosf(th, &s, &c);
            phases[(e * K + k) * 2]     = c;
            phases[(e * K + k) * 2 + 1] = s;
        }
    }
}

// fused kernel: first NPAINT blocks paint nonzero block pairs (plain stores);
// remaining NROW blocks stream zeros over unpainted complexes of one row each.
// The two write sets are disjoint at complex granularity -> no ordering hazard.
__global__ __launch_bounds__(256)
void fused_kernel(const float* __restrict__ hop, const float* __restrict__ ons,
                  const int* __restrict__ head, const int* __restrict__ nxt,
                  const int* __restrict__ pairlist, const int* __restrict__ counter,
                  const float* __restrict__ phases, float* __restrict__ out,
                  int npaint) {
    int t = threadIdx.x;
    if ((int)blockIdx.x < npaint) {
        // ---------------- paint ----------------
        int w = blockIdx.x;
        if (w >= *counter) return;
        if (t >= NORB * NORB) return;
        int pid = pairlist[w];
        int a = pid >> 8, b = pid & 255;
        int p = t / NORB, q = t - p * NORB;
        int i0, i1; float s0, s1;
        map_pq(p, q, i0, s0);   // entry (p,q) of assembled block
        map_pq(q, p, i1, s1);   // entry (q,p) — transposed contributions
        float ar[4] = {0.f, 0.f, 0.f, 0.f}, ai[4] = {0.f, 0.f, 0.f, 0.f};
        if (a == b) {
            const float* f = ons + (long)a * FEAT;
            float v = 0.f;
            if (i0 >= 0) v += s0 * f[i0];
            if (i1 >= 0) v += s1 * f[i1];
            #pragma unroll
            for (int k = 0; k < 4; ++k) ar[k] += v;
        }
        for (int it = head[pid]; it >= 0; it = nxt[it]) {
            int e = it >> 1, dir = it & 1;
            float hv;
            if (dir == 0) hv = (i0 >= 0) ? s0 * hop[(long)e * FEAT + i0] : 0.f;
            else          hv = (i1 >= 0) ? s1 * hop[(long)e * FEAT + i1] : 0.f;
            const float* ph = phases + (long)e * 8;
            if (dir == 0) {
                #pragma unroll
                for (int k = 0; k < 4; ++k) { ar[k] += ph[2*k] * hv; ai[k] += ph[2*k+1] * hv; }
            } else {        // conj(phase) * hop^T
                #pragma unroll
                for (int k = 0; k < 4; ++k) { ar[k] += ph[2*k] * hv; ai[k] -= ph[2*k+1] * hv; }
            }
        }
        long row = (long)a * NORB + p;
        long col = (long)b * NORB + q;
        #pragma unroll
        for (int k = 0; k < 4; ++k) {
            long off = (((long)k * NN + row) * NN + col) * 2;
            out[off]     = ar[k];
            out[off + 1] = ai[k];
        }
    } else {
        // ---------------- gated zero, one row per block ----------------
        int r = blockIdx.x - npaint;          // 0 .. NROW-1 (k-major rows)
        unsigned rl = (unsigned)r % NN;       // row within one k-matrix
        unsigned a  = rl / 13u;               // row block index
        __shared__ unsigned char pnt[256];
        pnt[t] = (t == (int)a) ? 1 : (head[a * 256u + (unsigned)t] >= 0 ? 1 : 0);
        __syncthreads();
        long rowbase = (long)r * (NN * 2);    // float offset of this row
        float4 z4 = make_float4(0.f, 0.f, 0.f, 0.f);
        float2 z2 = make_float2(0.f, 0.f);
        for (int f = t; f < NN / 2; f += 256) {   // 1664 float4 per row
            int c0 = 2 * f, c1 = 2 * f + 1;
            int b0 = c0 / 13, b1 = c1 / 13;
            bool p0 = pnt[b0] != 0;
            bool p1 = (b1 == b0) ? p0 : (pnt[b1] != 0);
            if (p0 && p1) continue;
            long off = rowbase + 4l * f;
            if (!p0 && !p1)      *(float4*)(out + off)     = z4;
            else if (!p0)        *(float2*)(out + off)     = z2;   // first complex only
            else                 *(float2*)(out + off + 2) = z2;   // second complex only
        }
    }
}

// ============================ FALLBACK PATH (round-2, proven) ================

__global__ void zero_kernel(float4* __restrict__ out, long n4) {
    long i = (long)blockIdx.x * blockDim.x + threadIdx.x;
    long stride = (long)gridDim.x * blockDim.x;
    float4 z = make_float4(0.f, 0.f, 0.f, 0.f);
    for (; i < n4; i += stride) out[i] = z;
}

template <int CPX>
__global__ void onsite_kernel(const float* __restrict__ onsite, float* __restrict__ out,
                              int K, long nn) {
    int a = blockIdx.x;
    int t = threadIdx.x;
    if (t >= NORB * NORB) return;
    int p = t / NORB, q = t % NORB;
    int i1, i2; float s1, s2;
    map_pq(p, q, i1, s1);
    map_pq(q, p, i2, s2);
    const float* f = onsite + (long)a * FEAT;
    float v = 0.0f;
    if (i1 >= 0) v += s1 * f[i1];
    if (i2 >= 0) v += s2 * f[i2];
    long row = (long)a * NORB + p;
    long col = (long)a * NORB + q;
    for (int k = 0; k < K; ++k) {
        long off = (((long)k * nn + row) * nn + col) * CPX;
        out[off] = v;
    }
}

template <int CPX>
__global__ void edge_kernel(const float* __restrict__ hop, const float* __restrict__ kpts,
                            const float* __restrict__ shift, const int* __restrict__ eidx,
                            float* __restrict__ out, int E, int K, long nn) {
    int e = blockIdx.x;
    int t = threadIdx.x;
    __shared__ float phc[16], phs[16];
    int ei = eidx[e];
    int ej = eidx[E + e];
    if (t < K && t < 16) {
        float rx = shift[(long)e * 3 + 0];
        float ry = shift[(long)e * 3 + 1];
        float rz = shift[(long)e * 3 + 2];
        float th = -TWO_PI * (kpts[t * 3 + 0] * rx + kpts[t * 3 + 1] * ry + kpts[t * 3 + 2] * rz);
        float s, c;
        __sincosf(th, &s, &c);
        phc[t] = c; phs[t] = s;
    }
    __syncthreads();
    if (t >= NORB * NORB) return;
    int p = t / NORB, q = t % NORB;
    int idx; float scl;
    map_pq(p, q, idx, scl);
    if (idx < 0) return;
    float v = scl * hop[(long)e * FEAT + idx];
    long r1 = (long)ei * NORB + p, c1 = (long)ej * NORB + q;
    long r2 = (long)ej * NORB + q, c2 = (long)ei * NORB + p;
    for (int k = 0; k < K; ++k) {
        float pr = phc[k], pi = phs[k];
        long o1 = (((long)k * nn + r1) * nn + c1) * CPX;
        long o2 = (((long)k * nn + r2) * nn + c2) * CPX;
        atomicAdd(&out[o1], pr * v);
        atomicAdd(&out[o2], pr * v);
        if (CPX == 2) {
            atomicAdd(&out[o1 + 1], pi * v);
            atomicAdd(&out[o2 + 1], -pi * v);
        }
    }
}

// ============================================================================

extern "C" void kernel_launch(void* const* d_in, const int* in_sizes, int n_in,
                              void* d_out, int out_size, void* d_ws, size_t ws_size,
                              hipStream_t stream) {
    const float* hop  = (const float*)d_in[0];
    const float* ons  = (const float*)d_in[1];
    const float* kpt  = (const float*)d_in[2];
    const float* shf  = (const float*)d_in[3];
    const int*   eidx = (const int*)d_in[4];

    int E = in_sizes[0] / FEAT;    // 4096
    int N = in_sizes[1] / FEAT;    // 256
    int K = in_sizes[2] / 3;       // 4
    long nn = (long)N * NORB;      // 3328

    float* out = (float*)d_out;
    long knn2 = (long)K * nn * nn * 2;

    // Workspace carving (16B-aligned offsets)
    size_t off_head  = 0;                                       // 65536 ints
    size_t off_next  = off_head + 65536 * sizeof(int);          // 2E ints
    size_t off_plist = off_next + (size_t)2 * E * sizeof(int);  // 256+2E ints
    size_t off_cnt   = off_plist + (size_t)(256 + 2 * E) * sizeof(int);
    size_t off_phase = (off_cnt + 4 + 127) & ~(size_t)127;      // E*K*2 floats
    size_t ws_need   = off_phase + (size_t)E * K * 2 * sizeof(float);

    bool fast = (N == 256) && (K == 4) && (nn == NN) &&
                ((long)out_size == knn2) && (ws_size >= ws_need);

    if (fast) {
        char* ws = (char*)d_ws;
        int*   head   = (int*)(ws + off_head);
        int*   nxt    = (int*)(ws + off_next);
        int*   plist  = (int*)(ws + off_plist);
        int*   cnt    = (int*)(ws + off_cnt);
        float* phases = (float*)(ws + off_phase);

        init_kernel<<<64, 256, 0, stream>>>((int4*)head, plist, cnt);
        fill_kernel<<<(2 * E + 255) / 256, 256, 0, stream>>>(eidx, kpt, shf, head, nxt,
                                                             plist, cnt, phases, E, K);
        int npaint = 256 + 2 * E;                 // 8448
        fused_kernel<<<npaint + NROW, 256, 0, stream>>>(hop, ons, head, nxt, plist,
                                                        cnt, phases, out, npaint);
    } else {
        // proven round-2 path
        int cpx = ((long)out_size >= knn2) ? 2 : 1;
        long n4 = (long)out_size / 4;
        zero_kernel<<<2048, 256, 0, stream>>>((float4*)out, n4);
        if (cpx == 2) {
            onsite_kernel<2><<<N, 192, 0, stream>>>(ons, out, K, nn);
            edge_kernel<2><<<E, 192, 0, stream>>>(hop, kpt, shf, eidx, out, E, K, nn);
        } else {
            onsite_kernel<1><<<N, 192, 0, stream>>>(ons, out, K, nn);
            edge_kernel<1><<<E, 192, 0, stream>>>(hop, kpt, shf, eidx, out, E, K, nn);
        }
    }
}

// Round 5
// 79.824 us; speedup vs baseline: 1.0144x; 1.0052x over previous
//
#include <hip/hip_runtime.h>

#define NORB 13
#define FEAT 107
#define TWO_PI 6.28318530717958647692f
#define NN 3328                 // 256 atoms * 13 orbitals
#define ROWF (NN * 2)           // floats per row = 6656
#define EMAX 4096

// Static device scratch (module-load allocated; no hipMalloc, graph-safe).
__device__ int   g_head[65536];       // per (a,b) block pair: list head or -1
__device__ int   g_nxt[2 * EMAX];     // directed-entry chain links
__device__ int   g_plist[256 + 2 * EMAX];
__device__ int   g_cnt;
__device__ float g_phases[EMAX * 4 * 2];   // [e][k][re,im]

// (p,q) in 13x13 block -> feature index (or -1) + scale.
// Basis l=[0,0,1,1,2], dims [1,1,3,3,5], offsets [0,1,2,5,8].
__device__ __forceinline__ void map_pq(int p, int q, int& idx, float& scl) {
    const int DIMS[5] = {1, 1, 3, 3, 5};
    const int OFFS[5] = {0, 1, 2, 5, 8};
    idx = -1; scl = 0.0f;
    int o = 0;
    #pragma unroll
    for (int i = 0; i < 5; ++i) {
        #pragma unroll
        for (int j = i; j < 5; ++j) {
            int di = DIMS[i], dj = DIMS[j];
            if (p >= OFFS[i] && p < OFFS[i] + di && q >= OFFS[j] && q < OFFS[j] + dj) {
                idx = o + (p - OFFS[i]) * dj + (q - OFFS[j]);
                scl = (i == j) ? 0.5f : 1.0f;
            }
            o += di * dj;
        }
    }
}

// ============================ FAST PATH =====================================

__global__ void init_kernel(int* __restrict__ pl_unused) {
    int t = blockIdx.x * blockDim.x + threadIdx.x;   // 16384 threads
    ((int4*)g_head)[t] = make_int4(-1, -1, -1, -1);
    if (t < 256) g_plist[t] = t * 257;               // diagonal pair ids
    if (t == 0) g_cnt = 256;
}

__global__ void fill_kernel(const int* __restrict__ eidx, const float* __restrict__ kpt,
                            const float* __restrict__ shf, int E, int K) {
    int tid = blockIdx.x * blockDim.x + threadIdx.x;
    if (tid >= 2 * E) return;
    int e = tid >> 1, dir = tid & 1;
    int ei = eidx[e], ej = eidx[E + e];
    int a = dir ? ej : ei;
    int b = dir ? ei : ej;
    int pid = a * 256 + b;
    int old = atomicExch(&g_head[pid], tid);
    g_nxt[tid] = old;
    if (old < 0 && a != b) {
        int pos = atomicAdd(&g_cnt, 1);
        g_plist[pos] = pid;
    }
    if (dir == 0) {
        float rx = shf[e * 3 + 0], ry = shf[e * 3 + 1], rz = shf[e * 3 + 2];
        for (int k = 0; k < K; ++k) {
            float th = -TWO_PI * (kpt[k * 3] * rx + kpt[k * 3 + 1] * ry + kpt[k * 3 + 2] * rz);
            float s, c;
            __sincosf(th, &s, &c);
            g_phases[(e * K + k) * 2]     = c;
            g_phases[(e * K + k) * 2 + 1] = s;
        }
    }
}

// fused: blocks [0, npaint) paint nonzero block pairs; blocks [npaint, +1024)
// stream zeros over unpainted complexes, one (k, atom) 13-row slab each.
// Write sets are disjoint at complex granularity -> no ordering hazard.
__global__ __launch_bounds__(256)
void fused_kernel(const float* __restrict__ hop, const float* __restrict__ ons,
                  float* __restrict__ out, int npaint) {
    int t = threadIdx.x;
    if ((int)blockIdx.x < npaint) {
        // ---------------- paint ----------------
        int w = blockIdx.x;
        if (w >= g_cnt) return;
        if (t >= NORB * NORB) return;
        int pid = g_plist[w];
        int a = pid >> 8, b = pid & 255;
        int p = t / NORB, q = t - p * NORB;
        int i0, i1; float s0, s1;
        map_pq(p, q, i0, s0);   // entry (p,q)
        map_pq(q, p, i1, s1);   // entry (q,p) — transposed contributions
        float ar[4] = {0.f, 0.f, 0.f, 0.f}, ai[4] = {0.f, 0.f, 0.f, 0.f};
        if (a == b) {
            const float* f = ons + (long)a * FEAT;
            float v = 0.f;
            if (i0 >= 0) v += s0 * f[i0];
            if (i1 >= 0) v += s1 * f[i1];
            #pragma unroll
            for (int k = 0; k < 4; ++k) ar[k] += v;
        }
        for (int it = g_head[pid]; it >= 0; it = g_nxt[it]) {
            int e = it >> 1, dir = it & 1;
            float hv;
            if (dir == 0) hv = (i0 >= 0) ? s0 * hop[(long)e * FEAT + i0] : 0.f;
            else          hv = (i1 >= 0) ? s1 * hop[(long)e * FEAT + i1] : 0.f;
            const float* ph = g_phases + e * 8;
            if (dir == 0) {
                #pragma unroll
                for (int k = 0; k < 4; ++k) { ar[k] += ph[2*k] * hv; ai[k] += ph[2*k+1] * hv; }
            } else {        // conj(phase) * hop^T
                #pragma unroll
                for (int k = 0; k < 4; ++k) { ar[k] += ph[2*k] * hv; ai[k] -= ph[2*k+1] * hv; }
            }
        }
        long row = (long)a * NORB + p;
        long col = (long)b * NORB + q;
        #pragma unroll
        for (int k = 0; k < 4; ++k) {
            long off = (((long)k * NN + row) * NN + col) * 2;
            out[off]     = ar[k];
            out[off + 1] = ai[k];
        }
    } else {
        // ------------- gated zero: one (k, atom) slab of 13 rows -------------
        int z = blockIdx.x - npaint;          // 0..1023
        int k = z >> 8;
        int a = z & 255;
        __shared__ unsigned char pnt[256];
        pnt[t] = (t == a) ? 1 : (g_head[a * 256 + t] >= 0 ? 1 : 0);
        __syncthreads();
        float4 z4 = make_float4(0.f, 0.f, 0.f, 0.f);
        float2 z2 = make_float2(0.f, 0.f);
        long slabbase = ((long)k * NN + (long)a * NORB) * ROWF;
        for (int rr = 0; rr < NORB; ++rr) {
            long rowbase = slabbase + (long)rr * ROWF;
            for (int f = t; f < NN / 2; f += 256) {   // 1664 float4 per row
                unsigned c0 = 2u * f, c1 = 2u * f + 1u;
                unsigned b0 = c0 / 13u, b1 = c1 / 13u;
                bool p0 = pnt[b0] != 0;
                bool p1 = (b1 == b0) ? p0 : (pnt[b1] != 0);
                if (p0 && p1) continue;
                long off = rowbase + 4l * f;
                if (!p0 && !p1)      *(float4*)(out + off)     = z4;
                else if (!p0)        *(float2*)(out + off)     = z2;
                else                 *(float2*)(out + off + 2) = z2;
            }
        }
    }
}

// ============================ FALLBACK PATH (round-2, proven) ================

__global__ void zero_kernel(float4* __restrict__ out, long n4) {
    long i = (long)blockIdx.x * blockDim.x + threadIdx.x;
    long stride = (long)gridDim.x * blockDim.x;
    float4 z = make_float4(0.f, 0.f, 0.f, 0.f);
    for (; i < n4; i += stride) out[i] = z;
}

template <int CPX>
__global__ void onsite_kernel(const float* __restrict__ onsite, float* __restrict__ out,
                              int K, long nn) {
    int a = blockIdx.x;
    int t = threadIdx.x;
    if (t >= NORB * NORB) return;
    int p = t / NORB, q = t % NORB;
    int i1, i2; float s1, s2;
    map_pq(p, q, i1, s1);
    map_pq(q, p, i2, s2);
    const float* f = onsite + (long)a * FEAT;
    float v = 0.0f;
    if (i1 >= 0) v += s1 * f[i1];
    if (i2 >= 0) v += s2 * f[i2];
    long row = (long)a * NORB + p;
    long col = (long)a * NORB + q;
    for (int k = 0; k < K; ++k) {
        long off = (((long)k * nn + row) * nn + col) * CPX;
        out[off] = v;
    }
}

template <int CPX>
__global__ void edge_kernel(const float* __restrict__ hop, const float* __restrict__ kpts,
                            const float* __restrict__ shift, const int* __restrict__ eidx,
                            float* __restrict__ out, int E, int K, long nn) {
    int e = blockIdx.x;
    int t = threadIdx.x;
    __shared__ float phc[16], phs[16];
    int ei = eidx[e];
    int ej = eidx[E + e];
    if (t < K && t < 16) {
        float rx = shift[(long)e * 3 + 0];
        float ry = shift[(long)e * 3 + 1];
        float rz = shift[(long)e * 3 + 2];
        float th = -TWO_PI * (kpts[t * 3 + 0] * rx + kpts[t * 3 + 1] * ry + kpts[t * 3 + 2] * rz);
        float s, c;
        __sincosf(th, &s, &c);
        phc[t] = c; phs[t] = s;
    }
    __syncthreads();
    if (t >= NORB * NORB) return;
    int p = t / NORB, q = t % NORB;
    int idx; float scl;
    map_pq(p, q, idx, scl);
    if (idx < 0) return;
    float v = scl * hop[(long)e * FEAT + idx];
    long r1 = (long)ei * NORB + p, c1 = (long)ej * NORB + q;
    long r2 = (long)ej * NORB + q, c2 = (long)ei * NORB + p;
    for (int k = 0; k < K; ++k) {
        float pr = phc[k], pi = phs[k];
        long o1 = (((long)k * nn + r1) * nn + c1) * CPX;
        long o2 = (((long)k * nn + r2) * nn + c2) * CPX;
        atomicAdd(&out[o1], pr * v);
        atomicAdd(&out[o2], pr * v);
        if (CPX == 2) {
            atomicAdd(&out[o1 + 1], pi * v);
            atomicAdd(&out[o2 + 1], -pi * v);
        }
    }
}

// ============================================================================

extern "C" void kernel_launch(void* const* d_in, const int* in_sizes, int n_in,
                              void* d_out, int out_size, void* d_ws, size_t ws_size,
                              hipStream_t stream) {
    const float* hop  = (const float*)d_in[0];
    const float* ons  = (const float*)d_in[1];
    const float* kpt  = (const float*)d_in[2];
    const float* shf  = (const float*)d_in[3];
    const int*   eidx = (const int*)d_in[4];

    int E = in_sizes[0] / FEAT;    // 4096
    int N = in_sizes[1] / FEAT;    // 256
    int K = in_sizes[2] / 3;       // 4
    long nn = (long)N * NORB;      // 3328

    float* out = (float*)d_out;
    long knn2 = (long)K * nn * nn * 2;

    bool fast = (N == 256) && (K == 4) && (E <= EMAX) &&
                ((long)out_size == knn2);

    if (fast) {
        init_kernel<<<64, 256, 0, stream>>>(nullptr);
        fill_kernel<<<(2 * E + 255) / 256, 256, 0, stream>>>(eidx, kpt, shf, E, K);
        int npaint = 256 + 2 * E;                 // 8448
        fused_kernel<<<npaint + 1024, 256, 0, stream>>>(hop, ons, out, npaint);
    } else {
        int cpx = ((long)out_size >= knn2) ? 2 : 1;
        long n4 = (long)out_size / 4;
        zero_kernel<<<2048, 256, 0, stream>>>((float4*)out, n4);
        if (cpx == 2) {
            onsite_kernel<2><<<N, 192, 0, stream>>>(ons, out, K, nn);
            edge_kernel<2><<<E, 192, 0, stream>>>(hop, kpt, shf, eidx, out, E, K, nn);
        } else {
            onsite_kernel<1><<<N, 192, 0, stream>>>(ons, out, K, nn);
            edge_kernel<1><<<E, 192, 0, stream>>>(hop, kpt, shf, eidx, out, E, K, nn);
        }
    }
}

// Round 6
// 79.763 us; speedup vs baseline: 1.0152x; 1.0008x over previous
//
#include <hip/hip_runtime.h>

#define NORB 13
#define FEAT 107
#define TWO_PI 6.28318530717958647692f
#define NN 3328                 // 256 atoms * 13 orbitals
#define ROWF (NN * 2)           // floats per row = 6656
#define EMAX 4096

typedef float f4 __attribute__((ext_vector_type(4)));

// Static device scratch (module-load allocated; no hipMalloc, graph-safe).
__device__ int   g_head[65536];          // per (a,b) block pair: list head or -1
__device__ int   g_nxt[2 * EMAX];        // directed-entry chain links
__device__ float g_phases[EMAX * 4 * 2]; // [e][k][re,im]

// (p,q) in 13x13 block -> feature index (or -1) + scale.
// Basis l=[0,0,1,1,2], dims [1,1,3,3,5], offsets [0,1,2,5,8].
__device__ __forceinline__ void map_pq(int p, int q, int& idx, float& scl) {
    const int DIMS[5] = {1, 1, 3, 3, 5};
    const int OFFS[5] = {0, 1, 2, 5, 8};
    idx = -1; scl = 0.0f;
    int o = 0;
    #pragma unroll
    for (int i = 0; i < 5; ++i) {
        #pragma unroll
        for (int j = i; j < 5; ++j) {
            int di = DIMS[i], dj = DIMS[j];
            if (p >= OFFS[i] && p < OFFS[i] + di && q >= OFFS[j] && q < OFFS[j] + dj) {
                idx = o + (p - OFFS[i]) * dj + (q - OFFS[j]);
                scl = (i == j) ? 0.5f : 1.0f;
            }
            o += di * dj;
        }
    }
}

// ============================ FAST PATH =====================================

__global__ void init_kernel() {
    int t = blockIdx.x * blockDim.x + threadIdx.x;   // 16384 threads
    ((int4*)g_head)[t] = make_int4(-1, -1, -1, -1);
}

__global__ void fill_kernel(const int* __restrict__ eidx, const float* __restrict__ kpt,
                            const float* __restrict__ shf, int E, int K) {
    int tid = blockIdx.x * blockDim.x + threadIdx.x;
    if (tid >= 2 * E) return;
    int e = tid >> 1, dir = tid & 1;
    int ei = eidx[e], ej = eidx[E + e];
    int a = dir ? ej : ei;
    int b = dir ? ei : ej;
    int pid = (a << 8) | b;
    int old = atomicExch(&g_head[pid], tid);
    g_nxt[tid] = old;
    if (dir == 0) {
        float rx = shf[e * 3 + 0], ry = shf[e * 3 + 1], rz = shf[e * 3 + 2];
        for (int k = 0; k < K; ++k) {
            float th = -TWO_PI * (kpt[k * 3] * rx + kpt[k * 3 + 1] * ry + kpt[k * 3 + 2] * rz);
            float s, c;
            __sincosf(th, &s, &c);
            g_phases[(e * K + k) * 2]     = c;
            g_phases[(e * K + k) * 2 + 1] = s;
        }
    }
}

// One block per (k, atom): gated-zero its 13-row slab, barrier, then paint all
// nonzero 13x13 blocks in those rows. Each output byte written by exactly one
// block; zero-vs-paint ordering enforced by __syncthreads().
__global__ __launch_bounds__(256)
void fused2_kernel(const float* __restrict__ hop, const float* __restrict__ ons,
                   float* __restrict__ out) {
    int z = blockIdx.x;            // 0..1023
    int k = z >> 8;
    int a = z & 255;
    int t = threadIdx.x;

    __shared__ int hd[256];
    __shared__ unsigned char pnt[256];
    __shared__ short pb[256];
    __shared__ int pbn;

    hd[t] = g_head[(a << 8) | t];
    if (t == 0) pbn = 0;
    __syncthreads();
    bool painted = (t == a) || (hd[t] >= 0);
    pnt[t] = painted ? 1 : 0;
    if (painted) {
        int s = atomicAdd(&pbn, 1);
        pb[s] = (short)t;
    }
    __syncthreads();

    // ---- zero phase: skip float4 only if BOTH complexes painted ----
    f4 z4 = {0.f, 0.f, 0.f, 0.f};
    long slabbase = ((long)k * NN + (long)a * NORB) * ROWF;
    for (int rr = 0; rr < NORB; ++rr) {
        long rowbase = slabbase + (long)rr * ROWF;
        for (int f = t; f < NN / 2; f += 256) {     // 1664 float4 per row
            unsigned b0 = (2u * f) / 13u;
            unsigned b1 = (2u * f + 1u) / 13u;
            if (pnt[b0] && pnt[b1]) continue;       // fully painted, skip
            __builtin_nontemporal_store(z4, (f4*)(out + rowbase + 4l * f));
        }
    }
    __syncthreads();

    // ---- paint phase: 169 threads, one (p,q) each, loop over painted b ----
    if (t < NORB * NORB) {
        int p = t / NORB, q = t - p * NORB;
        int i0, i1; float s0, s1;
        map_pq(p, q, i0, s0);   // entry (p,q)
        map_pq(q, p, i1, s1);   // entry (q,p) — transposed contributions
        int n = pbn;
        for (int s = 0; s < n; ++s) {
            int b = pb[s];
            float ar = 0.f, ai = 0.f;
            if (b == a) {       // onsite: M + M^T (real)
                const float* f = ons + (long)a * FEAT;
                if (i0 >= 0) ar += s0 * f[i0];
                if (i1 >= 0) ar += s1 * f[i1];
            }
            for (int it = hd[b]; it >= 0; it = g_nxt[it]) {
                int e = it >> 1, dir = it & 1;
                float hv;
                if (dir == 0) hv = (i0 >= 0) ? s0 * hop[(long)e * FEAT + i0] : 0.f;
                else          hv = (i1 >= 0) ? s1 * hop[(long)e * FEAT + i1] : 0.f;
                const float* ph = g_phases + e * 8 + k * 2;
                ar += ph[0] * hv;
                ai += (dir ? -ph[1] : ph[1]) * hv;
            }
            long off = (((long)k * NN + (long)a * NORB + p) * NN + (long)b * NORB + q) * 2;
            out[off]     = ar;
            out[off + 1] = ai;
        }
    }
}

// ============================ FALLBACK PATH (round-2, proven) ================

__global__ void zero_kernel(float4* __restrict__ out, long n4) {
    long i = (long)blockIdx.x * blockDim.x + threadIdx.x;
    long stride = (long)gridDim.x * blockDim.x;
    float4 zz = make_float4(0.f, 0.f, 0.f, 0.f);
    for (; i < n4; i += stride) out[i] = zz;
}

template <int CPX>
__global__ void onsite_kernel(const float* __restrict__ onsite, float* __restrict__ out,
                              int K, long nn) {
    int a = blockIdx.x;
    int t = threadIdx.x;
    if (t >= NORB * NORB) return;
    int p = t / NORB, q = t % NORB;
    int i1, i2; float s1, s2;
    map_pq(p, q, i1, s1);
    map_pq(q, p, i2, s2);
    const float* f = onsite + (long)a * FEAT;
    float v = 0.0f;
    if (i1 >= 0) v += s1 * f[i1];
    if (i2 >= 0) v += s2 * f[i2];
    long row = (long)a * NORB + p;
    long col = (long)a * NORB + q;
    for (int k = 0; k < K; ++k) {
        long off = (((long)k * nn + row) * nn + col) * CPX;
        out[off] = v;
    }
}

template <int CPX>
__global__ void edge_kernel(const float* __restrict__ hop, const float* __restrict__ kpts,
                            const float* __restrict__ shift, const int* __restrict__ eidx,
                            float* __restrict__ out, int E, int K, long nn) {
    int e = blockIdx.x;
    int t = threadIdx.x;
    __shared__ float phc[16], phs[16];
    int ei = eidx[e];
    int ej = eidx[E + e];
    if (t < K && t < 16) {
        float rx = shift[(long)e * 3 + 0];
        float ry = shift[(long)e * 3 + 1];
        float rz = shift[(long)e * 3 + 2];
        float th = -TWO_PI * (kpts[t * 3 + 0] * rx + kpts[t * 3 + 1] * ry + kpts[t * 3 + 2] * rz);
        float s, c;
        __sincosf(th, &s, &c);
        phc[t] = c; phs[t] = s;
    }
    __syncthreads();
    if (t >= NORB * NORB) return;
    int p = t / NORB, q = t % NORB;
    int idx; float scl;
    map_pq(p, q, idx, scl);
    if (idx < 0) return;
    float v = scl * hop[(long)e * FEAT + idx];
    long r1 = (long)ei * NORB + p, c1 = (long)ej * NORB + q;
    long r2 = (long)ej * NORB + q, c2 = (long)ei * NORB + p;
    for (int k = 0; k < K; ++k) {
        float pr = phc[k], pi = phs[k];
        long o1 = (((long)k * nn + r1) * nn + c1) * CPX;
        long o2 = (((long)k * nn + r2) * nn + c2) * CPX;
        atomicAdd(&out[o1], pr * v);
        atomicAdd(&out[o2], pr * v);
        if (CPX == 2) {
            atomicAdd(&out[o1 + 1], pi * v);
            atomicAdd(&out[o2 + 1], -pi * v);
        }
    }
}

// ============================================================================

extern "C" void kernel_launch(void* const* d_in, const int* in_sizes, int n_in,
                              void* d_out, int out_size, void* d_ws, size_t ws_size,
                              hipStream_t stream) {
    const float* hop  = (const float*)d_in[0];
    const float* ons  = (const float*)d_in[1];
    const float* kpt  = (const float*)d_in[2];
    const float* shf  = (const float*)d_in[3];
    const int*   eidx = (const int*)d_in[4];

    int E = in_sizes[0] / FEAT;    // 4096
    int N = in_sizes[1] / FEAT;    // 256
    int K = in_sizes[2] / 3;       // 4
    long nn = (long)N * NORB;      // 3328

    float* out = (float*)d_out;
    long knn2 = (long)K * nn * nn * 2;

    bool fast = (N == 256) && (K == 4) && (E <= EMAX) &&
                ((long)out_size == knn2);

    if (fast) {
        init_kernel<<<64, 256, 0, stream>>>();
        fill_kernel<<<(2 * E + 255) / 256, 256, 0, stream>>>(eidx, kpt, shf, E, K);
        fused2_kernel<<<1024, 256, 0, stream>>>(hop, ons, out);
    } else {
        int cpx = ((long)out_size >= knn2) ? 2 : 1;
        long n4 = (long)out_size / 4;
        zero_kernel<<<2048, 256, 0, stream>>>((float4*)out, n4);
        if (cpx == 2) {
            onsite_kernel<2><<<N, 192, 0, stream>>>(ons, out, K, nn);
            edge_kernel<2><<<E, 192, 0, stream>>>(hop, kpt, shf, eidx, out, E, K, nn);
        } else {
            onsite_kernel<1><<<N, 192, 0, stream>>>(ons, out, K, nn);
            edge_kernel<1><<<E, 192, 0, stream>>>(hop, kpt, shf, eidx, out, E, K, nn);
        }
    }
}